// Round 2
// baseline (1113.312 us; speedup 1.0000x reference)
//
#include <hip/hip_runtime.h>

#define NVOX 65536
#define CCH 64
#define HEADS 4
#define DH 16
#define KVOL 125
#define NPAIR 1048576

// ---------------------------------------------------------------------------
// Kernel 1: fused q/k/v projection + per-head L2 normalization of q,k.
// One wave (64 lanes) per voxel; lane = output channel. W matrices in LDS.
// ---------------------------------------------------------------------------
__global__ __launch_bounds__(256) void qkv_kernel(
    const float* __restrict__ x,
    const float* __restrict__ Wq, const float* __restrict__ bq,
    const float* __restrict__ Wk, const float* __restrict__ bk,
    const float* __restrict__ Wv, const float* __restrict__ bv,
    float* __restrict__ nq, float* __restrict__ nk, float* __restrict__ vbuf)
{
    __shared__ float wq_s[4096], wk_s[4096], wv_s[4096];
    __shared__ float xs[4][64];
    const int tid = threadIdx.x;
    for (int i = tid; i < 1024; i += 256) {
        ((float4*)wq_s)[i] = ((const float4*)Wq)[i];
        ((float4*)wk_s)[i] = ((const float4*)Wk)[i];
        ((float4*)wv_s)[i] = ((const float4*)Wv)[i];
    }
    const int lane = tid & 63;
    const int wid  = tid >> 6;
    const int n = blockIdx.x * 4 + wid;
    xs[wid][lane] = x[n * 64 + lane];
    __syncthreads();

    float accq = bq[lane];
    float acck = bk[lane];
    float accv = bv[lane];
    const float* xr = xs[wid];
    #pragma unroll 8
    for (int j = 0; j < 64; ++j) {
        const float xv = xr[j];
        accq += xv * wq_s[j * 64 + lane];
        acck += xv * wk_s[j * 64 + lane];
        accv += xv * wv_s[j * 64 + lane];
    }

    // per-head (16 consecutive lanes) sum of squares
    float sq = accq * accq;
    float sk = acck * acck;
    #pragma unroll
    for (int m = 1; m <= 8; m <<= 1) {
        sq += __shfl_xor(sq, m, 64);
        sk += __shfl_xor(sk, m, 64);
    }
    const float inq = accq / fmaxf(sqrtf(sq), 1e-12f);
    const float ink = acck / fmaxf(sqrtf(sk), 1e-12f);

    nq[n * 64 + lane]   = inq;
    nk[n * 64 + lane]   = ink;
    vbuf[n * 64 + lane] = accv;
}

// ---------------------------------------------------------------------------
// Kernel 2: normalize pos_enc [KVOL, H, D] per (kidx, head)
// ---------------------------------------------------------------------------
__global__ __launch_bounds__(64) void posnorm_kernel(
    const float* __restrict__ pos, float* __restrict__ npos)
{
    const int kidx = blockIdx.x;
    const int lane = threadIdx.x;
    const float pv = pos[kidx * 64 + lane];
    float s = pv * pv;
    #pragma unroll
    for (int m = 1; m <= 8; m <<= 1) s += __shfl_xor(s, m, 64);
    npos[kidx * 64 + lane] = pv / fmaxf(sqrtf(s), 1e-12f);
}

// ---------------------------------------------------------------------------
// Kernel 3: per-pair attention + scatter. 16 lanes per pair, lane owns float4
// of the 64-channel row. Head dot via shfl_xor over aligned 4-lane group.
// ---------------------------------------------------------------------------
__global__ __launch_bounds__(256) void pair_kernel(
    const int* __restrict__ kq_map,
    const float* __restrict__ nq, const float* __restrict__ nk,
    const float* __restrict__ npos, const float* __restrict__ vbuf,
    float* __restrict__ msg)
{
    const int gid  = blockIdx.x * 256 + threadIdx.x;
    const int pair = gid >> 4;
    const int l    = gid & 15;

    const unsigned kq = (unsigned)kq_map[pair];
    const int outv = kq_map[NPAIR + pair];
    const int inv  = (int)(kq / (unsigned)KVOL);
    const int kidx = (int)(kq - (unsigned)inv * (unsigned)KVOL);

    const float4 a  = ((const float4*)(nq   + (size_t)outv * 64))[l];
    const float4 b  = ((const float4*)(nk   + (size_t)inv  * 64))[l];
    const float4 c  = ((const float4*)(npos + (size_t)kidx * 64))[l];
    const float4 vv = ((const float4*)(vbuf + (size_t)inv  * 64))[l];

    float pdot = a.x * (b.x + c.x) + a.y * (b.y + c.y)
               + a.z * (b.z + c.z) + a.w * (b.w + c.w);
    // reduce over the 4 lanes of this head (lanes aligned mod 4)
    pdot += __shfl_xor(pdot, 1, 64);
    pdot += __shfl_xor(pdot, 2, 64);

    float* dst = msg + (size_t)outv * 64 + l * 4;
    atomicAdd(dst + 0, pdot * vv.x);
    atomicAdd(dst + 1, pdot * vv.y);
    atomicAdd(dst + 2, pdot * vv.z);
    atomicAdd(dst + 3, pdot * vv.w);
}

// ---------------------------------------------------------------------------
// Kernel 4: out = msg @ Wo + bo + x (residual), fp32 out
// ---------------------------------------------------------------------------
__global__ __launch_bounds__(256) void out_kernel(
    const float* __restrict__ msg,
    const float* __restrict__ Wo, const float* __restrict__ bo,
    const float* __restrict__ x, float* __restrict__ out)
{
    __shared__ float wo_s[4096];
    __shared__ float ms[4][64];
    const int tid = threadIdx.x;
    for (int i = tid; i < 1024; i += 256)
        ((float4*)wo_s)[i] = ((const float4*)Wo)[i];
    const int lane = tid & 63;
    const int wid  = tid >> 6;
    const int n = blockIdx.x * 4 + wid;
    ms[wid][lane] = msg[n * 64 + lane];
    __syncthreads();

    float acc = bo[lane];
    const float* mr = ms[wid];
    #pragma unroll 8
    for (int j = 0; j < 64; ++j) acc += mr[j] * wo_s[j * 64 + lane];

    acc += x[n * 64 + lane];
    out[n * 64 + lane] = acc;
}

// ---------------------------------------------------------------------------
extern "C" void kernel_launch(void* const* d_in, const int* in_sizes, int n_in,
                              void* d_out, int out_size, void* d_ws, size_t ws_size,
                              hipStream_t stream) {
    const float* x   = (const float*)d_in[0];
    const float* Wq  = (const float*)d_in[1];
    const float* bq  = (const float*)d_in[2];
    const float* Wk  = (const float*)d_in[3];
    const float* bk  = (const float*)d_in[4];
    const float* Wv  = (const float*)d_in[5];
    const float* bv  = (const float*)d_in[6];
    const float* Wo  = (const float*)d_in[7];
    const float* bo  = (const float*)d_in[8];
    const float* pos = (const float*)d_in[9];
    const int*   kq  = (const int*)d_in[10];

    float* ws   = (float*)d_ws;
    float* nq   = ws;                         // NVOX*64
    float* nk   = nq   + (size_t)NVOX * 64;   // NVOX*64
    float* vbuf = nk   + (size_t)NVOX * 64;   // NVOX*64
    float* npos = vbuf + (size_t)NVOX * 64;   // KVOL*64
    float* msg  = npos + (size_t)KVOL * 64;   // NVOX*64

    hipMemsetAsync(msg, 0, (size_t)NVOX * 64 * sizeof(float), stream);

    qkv_kernel<<<NVOX / 4, 256, 0, stream>>>(x, Wq, bq, Wk, bk, Wv, bv, nq, nk, vbuf);
    posnorm_kernel<<<KVOL, 64, 0, stream>>>(pos, npos);
    pair_kernel<<<(NPAIR * 16) / 256, 256, 0, stream>>>(kq, nq, nk, npos, vbuf, msg);
    out_kernel<<<NVOX / 4, 256, 0, stream>>>(msg, Wo, bo, x, (float*)d_out);
}

// Round 3
// 447.258 us; speedup vs baseline: 2.4892x; 2.4892x over previous
//
#include <hip/hip_runtime.h>

#define NVOX 65536
#define CCH 64
#define HEADS 4
#define DH 16
#define KVOL 125
#define NPAIR 1048576

// ---------------------------------------------------------------------------
// Kernel 1: fused q/k/v projection + per-head L2 normalization of q,k.
// One wave (64 lanes) per voxel; lane = output channel. W matrices in LDS.
// ---------------------------------------------------------------------------
__global__ __launch_bounds__(256) void qkv_kernel(
    const float* __restrict__ x,
    const float* __restrict__ Wq, const float* __restrict__ bq,
    const float* __restrict__ Wk, const float* __restrict__ bk,
    const float* __restrict__ Wv, const float* __restrict__ bv,
    float* __restrict__ nq, float* __restrict__ nk, float* __restrict__ vbuf)
{
    __shared__ float wq_s[4096], wk_s[4096], wv_s[4096];
    __shared__ float xs[4][64];
    const int tid = threadIdx.x;
    for (int i = tid; i < 1024; i += 256) {
        ((float4*)wq_s)[i] = ((const float4*)Wq)[i];
        ((float4*)wk_s)[i] = ((const float4*)Wk)[i];
        ((float4*)wv_s)[i] = ((const float4*)Wv)[i];
    }
    const int lane = tid & 63;
    const int wid  = tid >> 6;
    const int n = blockIdx.x * 4 + wid;
    xs[wid][lane] = x[n * 64 + lane];
    __syncthreads();

    float accq = bq[lane];
    float acck = bk[lane];
    float accv = bv[lane];
    const float* xr = xs[wid];
    #pragma unroll 8
    for (int j = 0; j < 64; ++j) {
        const float xv = xr[j];
        accq += xv * wq_s[j * 64 + lane];
        acck += xv * wk_s[j * 64 + lane];
        accv += xv * wv_s[j * 64 + lane];
    }

    // per-head (16 consecutive lanes) sum of squares
    float sq = accq * accq;
    float sk = acck * acck;
    #pragma unroll
    for (int m = 1; m <= 8; m <<= 1) {
        sq += __shfl_xor(sq, m, 64);
        sk += __shfl_xor(sk, m, 64);
    }
    const float inq = accq / fmaxf(sqrtf(sq), 1e-12f);
    const float ink = acck / fmaxf(sqrtf(sk), 1e-12f);

    nq[n * 64 + lane]   = inq;
    nk[n * 64 + lane]   = ink;
    vbuf[n * 64 + lane] = accv;
}

// ---------------------------------------------------------------------------
// Kernel 2: normalize pos_enc [KVOL, H, D] per (kidx, head)
// ---------------------------------------------------------------------------
__global__ __launch_bounds__(64) void posnorm_kernel(
    const float* __restrict__ pos, float* __restrict__ npos)
{
    const int kidx = blockIdx.x;
    const int lane = threadIdx.x;
    const float pv = pos[kidx * 64 + lane];
    float s = pv * pv;
    #pragma unroll
    for (int m = 1; m <= 8; m <<= 1) s += __shfl_xor(s, m, 64);
    npos[kidx * 64 + lane] = pv / fmaxf(sqrtf(s), 1e-12f);
}

// ---------------------------------------------------------------------------
// CSR binning: histogram of out_idx -> exclusive scan -> fill pair lists
// ---------------------------------------------------------------------------
__global__ __launch_bounds__(256) void hist_kernel(
    const int* __restrict__ kq_map, int* __restrict__ hist)
{
    const int p = blockIdx.x * 256 + threadIdx.x;
    atomicAdd(&hist[kq_map[NPAIR + p]], 1);
}

__global__ __launch_bounds__(1024) void scan_kernel(
    const int* __restrict__ hist, int* __restrict__ base, int* __restrict__ cursor)
{
    __shared__ int part[1024];
    const int t = threadIdx.x;
    int s = 0;
    for (int i = 0; i < 64; ++i) s += hist[t * 64 + i];
    part[t] = s;
    __syncthreads();
    for (int off = 1; off < 1024; off <<= 1) {
        int v = (t >= off) ? part[t - off] : 0;
        __syncthreads();
        part[t] += v;
        __syncthreads();
    }
    int excl = (t == 0) ? 0 : part[t - 1];
    for (int i = 0; i < 64; ++i) {
        const int h = hist[t * 64 + i];
        base[t * 64 + i]   = excl;
        cursor[t * 64 + i] = excl;
        excl += h;
    }
    if (t == 1023) base[NVOX] = part[1023];
}

__global__ __launch_bounds__(256) void fill_kernel(
    const int* __restrict__ kq_map, int* __restrict__ cursor, int* __restrict__ pairlist)
{
    const int p = blockIdx.x * 256 + threadIdx.x;
    const int o = kq_map[NPAIR + p];
    const int r = atomicAdd(&cursor[o], 1);
    pairlist[r] = p;
}

// ---------------------------------------------------------------------------
// Kernel 3: gather + attention + Wo projection + residual, fused. One wave
// per output voxel; 16 lanes per pair, 4 pairs in flight per wave. Register
// accumulation (no atomics), cross-pair-slot reduce via shfl_xor(16|32).
// ---------------------------------------------------------------------------
__global__ __launch_bounds__(256) void gather_out_kernel(
    const int* __restrict__ kq_map, const int* __restrict__ base,
    const int* __restrict__ pairlist,
    const float* __restrict__ nq, const float* __restrict__ nk,
    const float* __restrict__ npos, const float* __restrict__ vbuf,
    const float* __restrict__ Wo, const float* __restrict__ bo,
    const float* __restrict__ x, float* __restrict__ out)
{
    __shared__ float wo_s[4096];
    __shared__ float ms[4][64];
    const int tid = threadIdx.x;
    for (int i = tid; i < 1024; i += 256)
        ((float4*)wo_s)[i] = ((const float4*)Wo)[i];

    const int lane = tid & 63;
    const int wid  = tid >> 6;
    const int n  = blockIdx.x * 4 + wid;
    const int l  = lane & 15;   // float4 chunk of the 64-ch row (head = l>>2)
    const int pg = lane >> 4;   // pair slot (4 concurrent pairs)

    const float4 a = ((const float4*)(nq + (size_t)n * 64))[l];
    const int s = base[n];
    const int e = base[n + 1];

    float4 acc = make_float4(0.f, 0.f, 0.f, 0.f);
    for (int p = s + pg; p < e; p += 4) {
        const int pair = pairlist[p];
        const unsigned kqv = (unsigned)kq_map[pair];
        const int inv  = (int)(kqv / 125u);
        const int kidx = (int)(kqv - (unsigned)inv * 125u);
        const float4 b  = ((const float4*)(nk   + (size_t)inv  * 64))[l];
        const float4 c  = ((const float4*)(npos + (size_t)kidx * 64))[l];
        const float4 vv = ((const float4*)(vbuf + (size_t)inv  * 64))[l];
        float pdot = a.x * (b.x + c.x) + a.y * (b.y + c.y)
                   + a.z * (b.z + c.z) + a.w * (b.w + c.w);
        pdot += __shfl_xor(pdot, 1, 64);   // reduce within 4-lane head group
        pdot += __shfl_xor(pdot, 2, 64);
        acc.x += pdot * vv.x; acc.y += pdot * vv.y;
        acc.z += pdot * vv.z; acc.w += pdot * vv.w;
    }
    // reduce across the 4 pair slots (lanes l, l+16, l+32, l+48)
    acc.x += __shfl_xor(acc.x, 16, 64); acc.y += __shfl_xor(acc.y, 16, 64);
    acc.z += __shfl_xor(acc.z, 16, 64); acc.w += __shfl_xor(acc.w, 16, 64);
    acc.x += __shfl_xor(acc.x, 32, 64); acc.y += __shfl_xor(acc.y, 32, 64);
    acc.z += __shfl_xor(acc.z, 32, 64); acc.w += __shfl_xor(acc.w, 32, 64);

    if (pg == 0) ((float4*)ms[wid])[l] = acc;
    __syncthreads();

    // out = msg @ Wo + bo + x
    float o = bo[lane];
    const float* mr = ms[wid];
    #pragma unroll 8
    for (int j = 0; j < 64; ++j) o += mr[j] * wo_s[j * 64 + lane];
    out[n * 64 + lane] = o + x[n * 64 + lane];
}

// ---------------------------------------------------------------------------
extern "C" void kernel_launch(void* const* d_in, const int* in_sizes, int n_in,
                              void* d_out, int out_size, void* d_ws, size_t ws_size,
                              hipStream_t stream) {
    const float* x   = (const float*)d_in[0];
    const float* Wq  = (const float*)d_in[1];
    const float* bq  = (const float*)d_in[2];
    const float* Wk  = (const float*)d_in[3];
    const float* bk  = (const float*)d_in[4];
    const float* Wv  = (const float*)d_in[5];
    const float* bv  = (const float*)d_in[6];
    const float* Wo  = (const float*)d_in[7];
    const float* bo  = (const float*)d_in[8];
    const float* pos = (const float*)d_in[9];
    const int*   kq  = (const int*)d_in[10];

    float* ws   = (float*)d_ws;
    float* nq   = ws;                         // NVOX*64
    float* nk   = nq   + (size_t)NVOX * 64;   // NVOX*64
    float* vbuf = nk   + (size_t)NVOX * 64;   // NVOX*64
    float* npos = vbuf + (size_t)NVOX * 64;   // KVOL*64
    int* hist     = (int*)(npos + (size_t)KVOL * 64);  // NVOX
    int* base     = hist + NVOX;                       // NVOX+1
    int* cursor   = base + NVOX + 1;                   // NVOX
    int* pairlist = cursor + NVOX;                     // NPAIR

    hipMemsetAsync(hist, 0, (size_t)NVOX * sizeof(int), stream);

    qkv_kernel<<<NVOX / 4, 256, 0, stream>>>(x, Wq, bq, Wk, bk, Wv, bv, nq, nk, vbuf);
    posnorm_kernel<<<KVOL, 64, 0, stream>>>(pos, npos);
    hist_kernel<<<NPAIR / 256, 256, 0, stream>>>(kq, hist);
    scan_kernel<<<1, 1024, 0, stream>>>(hist, base, cursor);
    fill_kernel<<<NPAIR / 256, 256, 0, stream>>>(kq, cursor, pairlist);
    gather_out_kernel<<<NVOX / 4, 256, 0, stream>>>(kq, base, pairlist,
                                                    nq, nk, npos, vbuf,
                                                    Wo, bo, x, (float*)d_out);
}

// Round 4
// 356.612 us; speedup vs baseline: 3.1219x; 1.2542x over previous
//
#include <hip/hip_runtime.h>
#include <hip/hip_fp16.h>

#define NVOX 65536
#define KVOL 125
#define NPAIR 1048576

__device__ __forceinline__ float rdlane(float v, int j) {
    return __int_as_float(__builtin_amdgcn_readlane(__float_as_int(v), j));
}

// ---------------------------------------------------------------------------
// Kernel 1: fused q/k/v projection + per-head L2 norm. Persistent, 4-voxel
// batches per wave. W interleaved in LDS [j][c][3] -> merged LDS read.
// Outputs: nq fp32 [N][64]; kv packed fp16 interleaved per 16B chunk:
//   uint4 at chunk l = {k(4l),k(4l+1) | k(4l+2),k(4l+3) | v.. | v..}
// ---------------------------------------------------------------------------
__global__ __launch_bounds__(256, 3) void qkv_kernel(
    const float* __restrict__ x,
    const float* __restrict__ Wq, const float* __restrict__ bq,
    const float* __restrict__ Wk, const float* __restrict__ bk,
    const float* __restrict__ Wv, const float* __restrict__ bv,
    float* __restrict__ nq, unsigned int* __restrict__ kv)
{
    __shared__ float w_s[64 * 192];
    const int tid = threadIdx.x;
    for (int idx = tid; idx < 64 * 192; idx += 256) {
        const int j = idx / 192;
        const int r = idx - j * 192;
        const int c = r / 3;
        const int m = r - c * 3;
        w_s[idx] = (m == 0 ? Wq[j * 64 + c] : (m == 1 ? Wk[j * 64 + c] : Wv[j * 64 + c]));
    }
    __syncthreads();

    const int lane = tid & 63;
    const int wid  = tid >> 6;
    const int gw   = blockIdx.x * 4 + wid;      // 3072 waves
    const float bqv = bq[lane], bkv = bk[lane], bvv = bv[lane];
    const int t  = lane & 3;
    const int s0 = (lane & ~3) | ((t & 1) << 1);

    for (int nb = gw * 4; nb < NVOX; nb += 3072 * 4) {
        float xv[4], aq[4], ak[4], av[4];
        #pragma unroll
        for (int v = 0; v < 4; ++v) {
            xv[v] = x[(size_t)(nb + v) * 64 + lane];
            aq[v] = bqv; ak[v] = bkv; av[v] = bvv;
        }
        #pragma unroll 8
        for (int j = 0; j < 64; ++j) {
            const float w0 = w_s[j * 192 + lane * 3 + 0];
            const float w1 = w_s[j * 192 + lane * 3 + 1];
            const float w2 = w_s[j * 192 + lane * 3 + 2];
            #pragma unroll
            for (int v = 0; v < 4; ++v) {
                const float xj = rdlane(xv[v], j);
                aq[v] += xj * w0; ak[v] += xj * w1; av[v] += xj * w2;
            }
        }
        #pragma unroll
        for (int v = 0; v < 4; ++v) {
            float sq = aq[v] * aq[v];
            float sk = ak[v] * ak[v];
            #pragma unroll
            for (int m = 1; m <= 8; m <<= 1) {
                sq += __shfl_xor(sq, m);
                sk += __shfl_xor(sk, m);
            }
            const float inq = aq[v] / fmaxf(sqrtf(sq), 1e-12f);
            const float ink = ak[v] / fmaxf(sqrtf(sk), 1e-12f);
            nq[(size_t)(nb + v) * 64 + lane] = inq;
            // pack k,v fp16 into interleaved layout (2 shuffles)
            const unsigned hk = __half_as_ushort(__float2half(ink));
            const unsigned hv = __half_as_ushort(__float2half(av[v]));
            const unsigned combo = hk | (hv << 16);
            const unsigned g0 = (unsigned)__shfl((int)combo, s0);
            const unsigned g1 = (unsigned)__shfl((int)combo, s0 + 1);
            const unsigned b0 = (t >= 2) ? (g0 >> 16) : (g0 & 0xffffu);
            const unsigned b1 = (t >= 2) ? (g1 >> 16) : (g1 & 0xffffu);
            kv[(size_t)(nb + v) * 64 + lane] = b0 | (b1 << 16);
        }
    }
}

// ---------------------------------------------------------------------------
// Kernel 2: normalize pos_enc per (kidx, head), write fp16
// ---------------------------------------------------------------------------
__global__ __launch_bounds__(64) void posnorm_kernel(
    const float* __restrict__ pos, __half* __restrict__ nposh)
{
    const int kidx = blockIdx.x;
    const int lane = threadIdx.x;
    const float pv = pos[kidx * 64 + lane];
    float s = pv * pv;
    #pragma unroll
    for (int m = 1; m <= 8; m <<= 1) s += __shfl_xor(s, m);
    nposh[kidx * 64 + lane] = __float2half(pv / fmaxf(sqrtf(s), 1e-12f));
}

// ---------------------------------------------------------------------------
// CSR binning: histogram -> parallel scan (3 small kernels) -> fill (packed)
// ---------------------------------------------------------------------------
__global__ __launch_bounds__(256) void hist_kernel(
    const int* __restrict__ kq_map, int* __restrict__ hist)
{
    const int p = blockIdx.x * 256 + threadIdx.x;
    atomicAdd(&hist[kq_map[NPAIR + p]], 1);
}

__global__ __launch_bounds__(256) void scan1_kernel(
    const int* __restrict__ hist, int* __restrict__ bsum)
{
    __shared__ int red[256];
    const int tidx = threadIdx.x;
    red[tidx] = hist[blockIdx.x * 256 + tidx];
    __syncthreads();
    for (int off = 128; off > 0; off >>= 1) {
        if (tidx < off) red[tidx] += red[tidx + off];
        __syncthreads();
    }
    if (tidx == 0) bsum[blockIdx.x] = red[0];
}

__global__ __launch_bounds__(256) void scan2_kernel(
    const int* __restrict__ bsum, int* __restrict__ boffs, int* __restrict__ base)
{
    __shared__ int sc[256];
    const int tidx = threadIdx.x;
    const int own = bsum[tidx];
    sc[tidx] = own;
    __syncthreads();
    for (int off = 1; off < 256; off <<= 1) {
        const int v = (tidx >= off) ? sc[tidx - off] : 0;
        __syncthreads();
        sc[tidx] += v;
        __syncthreads();
    }
    boffs[tidx] = sc[tidx] - own;           // exclusive
    if (tidx == 255) base[NVOX] = sc[255];  // == NPAIR
}

__global__ __launch_bounds__(256) void scan3_kernel(
    const int* __restrict__ hist, const int* __restrict__ boffs,
    int* __restrict__ base, int* __restrict__ cursor)
{
    __shared__ int sc[256];
    const int tidx = threadIdx.x;
    const int gid = blockIdx.x * 256 + tidx;
    const int own = hist[gid];
    sc[tidx] = own;
    __syncthreads();
    for (int off = 1; off < 256; off <<= 1) {
        const int v = (tidx >= off) ? sc[tidx - off] : 0;
        __syncthreads();
        sc[tidx] += v;
        __syncthreads();
    }
    const int val = boffs[blockIdx.x] + sc[tidx] - own;
    base[gid] = val;
    cursor[gid] = val;
}

__global__ __launch_bounds__(256) void fill_kernel(
    const int* __restrict__ kq_map, int* __restrict__ cursor,
    unsigned int* __restrict__ pairlist)
{
    const int p = blockIdx.x * 256 + threadIdx.x;
    const unsigned kqv = (unsigned)kq_map[p];
    const int o = kq_map[NPAIR + p];
    const unsigned inv = kqv / 125u;
    const unsigned kidx = kqv - inv * 125u;
    const int r = atomicAdd(&cursor[o], 1);
    pairlist[r] = (inv << 7) | kidx;
}

// ---------------------------------------------------------------------------
// Kernel 3: gather + attention + Wo projection + residual. Persistent 1024
// blocks; Wo + npos staged in LDS once. fp16 kv gathers (one uint4 per lane
// per pair). Epilogue: j-quartered b128 Wo reads, broadcast ms reads.
// ---------------------------------------------------------------------------
__global__ __launch_bounds__(256, 4) void gather_out_kernel(
    const int* __restrict__ base, const unsigned int* __restrict__ pairlist,
    const float* __restrict__ nq, const unsigned int* __restrict__ kv,
    const __half* __restrict__ nposh,
    const float* __restrict__ Wo, const float* __restrict__ bo,
    const float* __restrict__ x, float* __restrict__ out)
{
    __shared__ float wo_s[4096];
    __shared__ __half npos_s[8192];
    __shared__ float ms[4][4][64];
    const int tid = threadIdx.x;
    for (int i = tid; i < 1024; i += 256) ((float4*)wo_s)[i] = ((const float4*)Wo)[i];
    for (int i = tid; i < 1000; i += 256) ((uint4*)npos_s)[i] = ((const uint4*)nposh)[i];
    __syncthreads();

    const int lane = tid & 63;
    const int wid  = tid >> 6;
    const int l    = lane & 15;
    const int pg   = lane >> 4;
    const int cc   = l * 4;
    const int gw   = blockIdx.x * 4 + wid;   // 4096 waves
    const float4 bo4 = *(const float4*)&bo[cc];

    for (int nb = gw * 4; nb < NVOX; nb += 4096 * 4) {
        // ---- pair phase: 4 voxels, register accumulation ----
        #pragma unroll
        for (int v = 0; v < 4; ++v) {
            const int n = nb + v;
            const float4 a4 = ((const float4*)(nq + (size_t)n * 64))[l];
            const int s = base[n];
            const int e = base[n + 1];
            float4 acc = make_float4(0.f, 0.f, 0.f, 0.f);
            for (int p = s + pg; p < e; p += 4) {
                const unsigned pk = pairlist[p];
                const int inv  = (int)(pk >> 7);
                const int kidx = (int)(pk & 127u);
                const uint4 u = *(const uint4*)(kv + (size_t)inv * 64 + cc);
                const float2 k01 = __half22float2(*(const __half2*)&u.x);
                const float2 k23 = __half22float2(*(const __half2*)&u.y);
                const float2 v01 = __half22float2(*(const __half2*)&u.z);
                const float2 v23 = __half22float2(*(const __half2*)&u.w);
                const __half2* np = (const __half2*)&npos_s[kidx * 64 + cc];
                const float2 c01 = __half22float2(np[0]);
                const float2 c23 = __half22float2(np[1]);
                float pdot = a4.x * (k01.x + c01.x) + a4.y * (k01.y + c01.y)
                           + a4.z * (k23.x + c23.x) + a4.w * (k23.y + c23.y);
                pdot += __shfl_xor(pdot, 1);
                pdot += __shfl_xor(pdot, 2);
                acc.x += pdot * v01.x; acc.y += pdot * v01.y;
                acc.z += pdot * v23.x; acc.w += pdot * v23.y;
            }
            acc.x += __shfl_xor(acc.x, 16); acc.y += __shfl_xor(acc.y, 16);
            acc.z += __shfl_xor(acc.z, 16); acc.w += __shfl_xor(acc.w, 16);
            acc.x += __shfl_xor(acc.x, 32); acc.y += __shfl_xor(acc.y, 32);
            acc.z += __shfl_xor(acc.z, 32); acc.w += __shfl_xor(acc.w, 32);
            if (pg == 0) *(float4*)&ms[wid][v][cc] = acc;
        }
        // ---- epilogue: out = msg @ Wo + bo + x  (j split across quarters) ----
        float4 o4[4];
        #pragma unroll
        for (int v = 0; v < 4; ++v) o4[v] = make_float4(0.f, 0.f, 0.f, 0.f);
        #pragma unroll
        for (int ib = 0; ib < 4; ++ib) {
            float4 mq[4];
            #pragma unroll
            for (int v = 0; v < 4; ++v)
                mq[v] = *(const float4*)&ms[wid][v][pg * 16 + ib * 4];
            #pragma unroll
            for (int tt = 0; tt < 4; ++tt) {
                const int j = pg * 16 + ib * 4 + tt;
                const float4 w4 = *(const float4*)&wo_s[j * 64 + cc];
                #pragma unroll
                for (int v = 0; v < 4; ++v) {
                    const float m = (tt == 0 ? mq[v].x : tt == 1 ? mq[v].y :
                                     tt == 2 ? mq[v].z : mq[v].w);
                    o4[v].x += m * w4.x; o4[v].y += m * w4.y;
                    o4[v].z += m * w4.z; o4[v].w += m * w4.w;
                }
            }
        }
        #pragma unroll
        for (int v = 0; v < 4; ++v) {
            o4[v].x += __shfl_xor(o4[v].x, 16); o4[v].y += __shfl_xor(o4[v].y, 16);
            o4[v].z += __shfl_xor(o4[v].z, 16); o4[v].w += __shfl_xor(o4[v].w, 16);
            o4[v].x += __shfl_xor(o4[v].x, 32); o4[v].y += __shfl_xor(o4[v].y, 32);
            o4[v].z += __shfl_xor(o4[v].z, 32); o4[v].w += __shfl_xor(o4[v].w, 32);
        }
        if (pg == 0) {
            #pragma unroll
            for (int v = 0; v < 4; ++v) {
                const float4 xr = *(const float4*)&x[(size_t)(nb + v) * 64 + cc];
                float4 r;
                r.x = o4[v].x + bo4.x + xr.x;
                r.y = o4[v].y + bo4.y + xr.y;
                r.z = o4[v].z + bo4.z + xr.z;
                r.w = o4[v].w + bo4.w + xr.w;
                *(float4*)&out[(size_t)(nb + v) * 64 + cc] = r;
            }
        }
    }
}

// ---------------------------------------------------------------------------
extern "C" void kernel_launch(void* const* d_in, const int* in_sizes, int n_in,
                              void* d_out, int out_size, void* d_ws, size_t ws_size,
                              hipStream_t stream) {
    const float* x   = (const float*)d_in[0];
    const float* Wq  = (const float*)d_in[1];
    const float* bq  = (const float*)d_in[2];
    const float* Wk  = (const float*)d_in[3];
    const float* bk  = (const float*)d_in[4];
    const float* Wv  = (const float*)d_in[5];
    const float* bv  = (const float*)d_in[6];
    const float* Wo  = (const float*)d_in[7];
    const float* bo  = (const float*)d_in[8];
    const float* pos = (const float*)d_in[9];
    const int*   kq  = (const int*)d_in[10];

    char* w = (char*)d_ws;
    float*        nq       = (float*)w;        w += (size_t)NVOX * 64 * 4;   // 16 MB
    unsigned int* kv       = (unsigned int*)w; w += (size_t)NVOX * 64 * 4;   // 16 MB
    unsigned int* pairlist = (unsigned int*)w; w += (size_t)NPAIR * 4;       // 4 MB
    int*          hist     = (int*)w;          w += (size_t)NVOX * 4;        // 256 KB
    int*          cursor   = (int*)w;          w += (size_t)NVOX * 4;        // 256 KB
    int*          bsum     = (int*)w;          w += 256 * 4;
    int*          boffs    = (int*)w;          w += 256 * 4;
    __half*       nposh    = (__half*)w;       w += 16384;                   // 16 KB (16000 used)
    int*          base     = (int*)w;          w += (size_t)(NVOX + 1) * 4;

    hipMemsetAsync(hist, 0, (size_t)NVOX * sizeof(int), stream);

    qkv_kernel<<<768, 256, 0, stream>>>(x, Wq, bq, Wk, bk, Wv, bv, nq, kv);
    posnorm_kernel<<<KVOL, 64, 0, stream>>>(pos, nposh);
    hist_kernel<<<NPAIR / 256, 256, 0, stream>>>(kq, hist);
    scan1_kernel<<<256, 256, 0, stream>>>(hist, bsum);
    scan2_kernel<<<1, 256, 0, stream>>>(bsum, boffs, base);
    scan3_kernel<<<256, 256, 0, stream>>>(hist, boffs, base, cursor);
    fill_kernel<<<NPAIR / 256, 256, 0, stream>>>(kq, cursor, pairlist);
    gather_out_kernel<<<1024, 256, 0, stream>>>(base, pairlist, nq, kv, nposh,
                                                Wo, bo, x, (float*)d_out);
}